// Round 13
// baseline (29.492 us; speedup 1.0000x reference)
//
#include <hip/hip_runtime.h>

// RuleNet: out[b] = 5 + sum_c rw[c] * min_j( mu[c,j]*x[b,j] + (1-mu[c,j]) )
// x = [x0, 1-x0], mu = sigmoid(conjunctions).
// fit(b,c) = 1 - max_v max( mu1*(1-x), mu2*x );  mu1*(1-x) = fma(-mu1,x,mu1).
//
// R13: GEMM-style 2-D register blocking. Lane owns 8b x 4c acc tile (32 regs);
// per v-step: 4 ds_read_b128 -> 96 VALU (24:1 arith:load vs ~6:1 before).
// Block tile 64b x 32c, full v=256 in 2 LDS chunks of 128; 8 waves v-split.
// x LDS tile granule-16 XOR swizzled (read-side folds to ib2^k, 2-way=free).
// mu pre-packed by k_prep so LDS staging is row-major (conflict-light).
// Epilogue: 3-round LDS max-tree (stride-33), weight, shfl-sum, 64 atomics.

#define B_    1024
#define C_    512
#define V_    256

#define BT    64               // b-tile per block
#define CT    32               // c-tile per block
#define VC    128              // v chunk (2 chunks cover V_)

// ---------- kernel 1: sigmoid + pack, plus out=5.0 init ----------
// muP[v][(c>>2)*8 + half*4 + (c&3)] : per v-row, jc-group g holds
// (mu1[g*4..+4], mu2[g*4..+4]) contiguously -> k_main stages rows directly.
__global__ __launch_bounds__(256) void k_prep(const float* __restrict__ conj,
                                              float* __restrict__ muP,
                                              float* __restrict__ out) {
    const int c = blockIdx.x;        // 512
    const int v = threadIdx.x;       // 256, coalesced conj reads
    if (c < 4) out[c * 256 + v] = 5.0f;
    float z1 = conj[(size_t)c * 512 + v];
    float z2 = conj[(size_t)c * 512 + 256 + v];
    float m1 = 1.0f / (1.0f + __expf(-z1));
    float m2 = 1.0f / (1.0f + __expf(-z2));
    size_t base = (size_t)v * 1024 + (size_t)(c >> 2) * 8 + (c & 3);
    muP[base]     = m1;
    muP[base + 4] = m2;
}

// ---------- kernel 2: register-blocked fuzzy-AND ----------
__global__ __launch_bounds__(512, 2) void k_main(const float* __restrict__ x0,
                                                 const float* __restrict__ muP,
                                                 const float* __restrict__ rw,
                                                 float* __restrict__ out) {
    __shared__ float lds[16384];                 // 64 KB: x[0,8192) mu[8192,16384)
    const int tid  = threadIdx.x;
    const int lane = tid & 63;
    const int w    = tid >> 6;                   // wave: v-split owner
    const int ib   = lane & 7;                   // b-group (8 b each)
    const int jc   = lane >> 3;                  // c-group (4 c each)
    const int b0   = blockIdx.x * BT;
    const int c0   = blockIdx.y * CT;
    const int ib2  = ib * 2;

    float m[8][4];
#pragma unroll
    for (int bb = 0; bb < 8; ++bb)
#pragma unroll
        for (int cc = 0; cc < 4; ++cc) m[bb][cc] = 0.0f;

    const int xw   = w * 1024;                   // (w*16)*64 floats
    const int mu_b = 8192 + w * 1024 + jc * 8;

#define STAGE(h) do { \
    _Pragma("unroll") \
    for (int it = 0; it < 4; ++it) {             /* x: 2048 f4, swizzled write */ \
        int idx = it * 512 + tid; \
        int b = idx >> 5, v4 = idx & 31; \
        float4 xv = *reinterpret_cast<const float4*>( \
            &x0[(size_t)(b0 + b) * 256 + (h) * 128 + v4 * 4]); \
        int vb = v4 * 4, gb = b >> 2, bl = b & 3; \
        lds[(vb+0)*64 + ((gb ^ ((vb+0)&15)) << 2) + bl] = xv.x; \
        lds[(vb+1)*64 + ((gb ^ ((vb+1)&15)) << 2) + bl] = xv.y; \
        lds[(vb+2)*64 + ((gb ^ ((vb+2)&15)) << 2) + bl] = xv.z; \
        lds[(vb+3)*64 + ((gb ^ ((vb+3)&15)) << 2) + bl] = xv.w; \
    } \
    _Pragma("unroll") \
    for (int it = 0; it < 4; ++it) {             /* mu: row-major copy */ \
        int idx = it * 512 + tid; \
        int o4 = idx & 15, vl = idx >> 4; \
        float4 mv = *reinterpret_cast<const float4*>( \
            &muP[(size_t)((h) * 128 + vl) * 1024 + c0 * 2 + o4 * 4]); \
        *reinterpret_cast<float4*>(&lds[8192 + vl * 64 + o4 * 4]) = mv; \
    } } while (0)

#define COMPUTE() do { \
    _Pragma("unroll") \
    for (int k = 0; k < 16; ++k) { \
        int xi = xw + k * 64 + ((ib2 ^ k) << 2); \
        float4 xa = *reinterpret_cast<const float4*>(&lds[xi]); \
        float4 xb = *reinterpret_cast<const float4*>(&lds[xi ^ 4]); \
        float4 av = *reinterpret_cast<const float4*>(&lds[mu_b + k * 64]); \
        float4 qv = *reinterpret_cast<const float4*>(&lds[mu_b + k * 64 + 4]); \
        float xs[8] = {xa.x, xa.y, xa.z, xa.w, xb.x, xb.y, xb.z, xb.w}; \
        float as[4] = {av.x, av.y, av.z, av.w}; \
        float qs[4] = {qv.x, qv.y, qv.z, qv.w}; \
        _Pragma("unroll") \
        for (int bb = 0; bb < 8; ++bb) \
        _Pragma("unroll") \
        for (int cc = 0; cc < 4; ++cc) \
            m[bb][cc] = fmaxf(m[bb][cc], \
                fmaxf(__builtin_fmaf(-as[cc], xs[bb], as[cc]), qs[cc] * xs[bb])); \
    } } while (0)

    STAGE(0);
    __syncthreads();
    COMPUTE();                    // chunk 0 (v 0..127, this wave: w*16..w*16+16)
    __syncthreads();
    STAGE(1);
    __syncthreads();
    COMPUTE();                    // chunk 1

#undef COMPUTE
#undef STAGE

    // ---- epilogue: max-combine the 8 wave v-splits (3-round LDS tree) ----
    __syncthreads();              // chunk-1 reads done; red overlays lds
#define RED(wi, l, kk) lds[(((wi) * 64 + (l)) * 33) + (kk)]
    if (w >= 4) {
#pragma unroll
        for (int kk = 0; kk < 32; ++kk) RED(w - 4, lane, kk) = m[kk >> 2][kk & 3];
    }
    __syncthreads();
    if (w < 4) {
#pragma unroll
        for (int kk = 0; kk < 32; ++kk)
            m[kk >> 2][kk & 3] = fmaxf(m[kk >> 2][kk & 3], RED(w, lane, kk));
    }
    __syncthreads();
    if (w == 2 || w == 3) {
#pragma unroll
        for (int kk = 0; kk < 32; ++kk) RED(w - 2, lane, kk) = m[kk >> 2][kk & 3];
    }
    __syncthreads();
    if (w < 2) {
#pragma unroll
        for (int kk = 0; kk < 32; ++kk)
            m[kk >> 2][kk & 3] = fmaxf(m[kk >> 2][kk & 3], RED(w, lane, kk));
    }
    __syncthreads();
    if (w == 1) {
#pragma unroll
        for (int kk = 0; kk < 32; ++kk) RED(0, lane, kk) = m[kk >> 2][kk & 3];
    }
    __syncthreads();
    if (w == 0) {
#pragma unroll
        for (int kk = 0; kk < 32; ++kk)
            m[kk >> 2][kk & 3] = fmaxf(m[kk >> 2][kk & 3], RED(0, lane, kk));
#undef RED
        float4 rwv = *reinterpret_cast<const float4*>(&rw[c0 + jc * 4]);
        float rr[4] = {rwv.x, rwv.y, rwv.z, rwv.w};
        float val[8];
#pragma unroll
        for (int bb = 0; bb < 8; ++bb) {
            float s = rr[0] * (1.0f - m[bb][0]);
            s = __builtin_fmaf(rr[1], 1.0f - m[bb][1], s);
            s = __builtin_fmaf(rr[2], 1.0f - m[bb][2], s);
            s = __builtin_fmaf(rr[3], 1.0f - m[bb][3], s);
            val[bb] = s;
        }
#pragma unroll
        for (int bb = 0; bb < 8; ++bb) {
            val[bb] += __shfl_xor(val[bb], 8, 64);
            val[bb] += __shfl_xor(val[bb], 16, 64);
            val[bb] += __shfl_xor(val[bb], 32, 64);
        }
        if (jc == 0) {
#pragma unroll
            for (int bb = 0; bb < 8; ++bb)
                atomicAdd(&out[b0 + ib * 8 + bb], val[bb]);  // 16 adds/element
        }
    }
}

// ---------- fallback (ws too small): naive but correct ----------
__global__ __launch_bounds__(256) void k_naive(const float* __restrict__ x0,
                                               const float* __restrict__ conj,
                                               const float* __restrict__ rw,
                                               float* __restrict__ out) {
    int b = blockIdx.x;
    int t = threadIdx.x;
    __shared__ float red[256];
    float acc = 0.0f;
    for (int c = t; c < C_; c += 256) {
        float mm = 0.0f;
        for (int v = 0; v < V_; ++v) {
            float mu1 = 1.0f / (1.0f + expf(-conj[(size_t)c * 512 + v]));
            float mu2 = 1.0f / (1.0f + expf(-conj[(size_t)c * 512 + 256 + v]));
            float x = x0[(size_t)b * V_ + v];
            mm = fmaxf(mm, fmaxf(mu1 * (1.0f - x), mu2 * x));
        }
        acc += rw[c] * (1.0f - mm);
    }
    red[t] = acc;
    __syncthreads();
    for (int s = 128; s > 0; s >>= 1) {
        if (t < s) red[t] += red[t + s];
        __syncthreads();
    }
    if (t == 0) out[b] = 5.0f + red[0];
}

extern "C" void kernel_launch(void* const* d_in, const int* in_sizes, int n_in,
                              void* d_out, int out_size, void* d_ws, size_t ws_size,
                              hipStream_t stream) {
    const float* x0   = (const float*)d_in[0];
    const float* conj = (const float*)d_in[1];
    const float* rw   = (const float*)d_in[2];
    float* out = (float*)d_out;

    const size_t mu_floats = (size_t)V_ * 1024;   // 262144 floats (1 MB)
    const size_t need = mu_floats * sizeof(float);

    if (ws_size < need) {
        k_naive<<<B_, 256, 0, stream>>>(x0, conj, rw, out);
        return;
    }

    float* muP = (float*)d_ws;

    k_prep<<<C_, 256, 0, stream>>>(conj, muP, out);
    dim3 grid(B_ / BT, C_ / CT);   // 16 x 16 = 256 blocks, 512 thr, 1/CU
    k_main<<<grid, 512, 0, stream>>>(x0, muP, rw, out);
}

// Round 14
// 22.668 us; speedup vs baseline: 1.3011x; 1.3011x over previous
//
#include <hip/hip_runtime.h>

// RuleNet: out[b] = 5 + sum_c rw[c] * min_j( mu[c,j]*x[b,j] + (1-mu[c,j]) )
// x = [x0, 1-x0], mu = sigmoid(conjunctions).
// fit(b,c) = 1 - max_v max( mu1*(1-x), mu2*x );  mu1*(1-x) = fma(-mu1,x,mu1).
//
// R14: R12 geometry, but the mu stream uses ASM global_load_dwordx4 with
// hand-counted s_waitcnt vmcnt(4/2/0) (T4: never drain to 0 mid-loop),
// 3-buffer rotation, depth-2 prefetch. x via LDS broadcast ds_read_b128
// (in-order lgkmcnt, compiler-graded). NO compiler-visible VMEM in the
// loop -> no hidden vmcnt(0) drains (R12's SMEM x had per-step ooo drains).

#define B_    1024
#define C_    512
#define V_    256
#define TWOV  512

#define BPB    8               // batches per block
#define NBG    (B_ / BPB)      // 128 b-groups
#define NCH    4               // c-chunks of 128

typedef float f32x4 __attribute__((ext_vector_type(4)));

// ---------- kernel 1: sigmoid + transpose (R8/R12 layout), + out=5.0 init ----
// float4 muT4[vp][c] = (mu1[2vp], mu2[2vp], mu1[2vp+1], mu2[2vp+1])
__global__ __launch_bounds__(256) void k_prep(const float* __restrict__ conj,
                                              float2* __restrict__ muT2,
                                              float* __restrict__ out) {
    const int c = blockIdx.x;        // 512 blocks
    const int v = threadIdx.x;       // 256 threads, coalesced loads
    if (c < 4) out[c * 256 + v] = 5.0f;
    float z1 = conj[(size_t)c * TWOV + v];
    float z2 = conj[(size_t)c * TWOV + V_ + v];
    float m1 = 1.0f / (1.0f + __expf(-z1));
    float m2 = 1.0f / (1.0f + __expf(-z2));
    muT2[(size_t)(v >> 1) * (2 * C_) + c * 2 + (v & 1)] = make_float2(m1, m2);
}

// ---------- kernel 2: main fuzzy-AND ----------
__global__ __launch_bounds__(512, 4) void k_main(const float* __restrict__ x0,
                                                 const f32x4* __restrict__ muT4,
                                                 const float* __restrict__ rw,
                                                 float* __restrict__ out) {
    const int tid  = threadIdx.x;
    const int lane = tid & 63;
    const int wave = tid >> 6;
    const int t    = wave & 1;                   // c-half (64 c)
    const int s    = wave >> 1;                  // v-quarter (64 v)
    const int bg   = blockIdx.x;                 // 128 groups of 8 batches
    const int chunk= blockIdx.y;                 // 4 chunks of 128 c
    const int c    = chunk * 128 + t * 64 + lane;
    const int xq   = s * 16;                     // this wave's f32x4 base in xs

    __shared__ f32x4 xs4[BPB * V_ / 4];          // 8 KB x tile
    __shared__ float red[4 * 128 * 9];           // 18 KB epilogue tree

    // stage x (compiler load + ds_write; its vmcnt(0) fires BEFORE asm loads)
    {
        const f32x4* xg = reinterpret_cast<const f32x4*>(x0 + (size_t)bg * BPB * V_);
        xs4[tid] = xg[tid];
    }

    // per-lane mu pointers; advance 2 vp-rows (4 v) per step
    const f32x4* mu1p = muT4 + (size_t)(s * 32) * C_ + c;
    const f32x4* mu2p = mu1p + C_;

    float m[BPB];
#pragma unroll
    for (int i = 0; i < BPB; ++i) m[i] = 0.0f;

    f32x4 A0, B0, A1, B1, A2, B2;                // 3 rotating mu buffers

#define MULOAD(DST, PTR) \
    asm volatile("global_load_dwordx4 %0, %1, off" : "=v"(DST) : "v"(PTR))
#define ISSUE(MA, MB) do { \
    MULOAD(MA, mu1p); MULOAD(MB, mu2p); \
    mu1p += 2 * C_; mu2p += 2 * C_; } while (0)

    // prologue: q0, q1 in flight (4 outstanding)
    ISSUE(A0, B0);
    ISSUE(A1, B1);

    __syncthreads();   // x tile ready (drains prologue mu too - one-time cost)

#define COMPUTE(q, MA, MB) do { \
    _Pragma("unroll") \
    for (int bi = 0; bi < BPB; ++bi) { \
        f32x4 xc = xs4[bi * 64 + xq + (q)]; \
        float mm = m[bi]; \
        mm = fmaxf(fmaxf(__builtin_fmaf(-MA.x, xc.x, MA.x), MA.y * xc.x), mm); \
        mm = fmaxf(fmaxf(__builtin_fmaf(-MA.z, xc.y, MA.z), MA.w * xc.y), mm); \
        mm = fmaxf(fmaxf(__builtin_fmaf(-MB.x, xc.z, MB.x), MB.y * xc.z), mm); \
        mm = fmaxf(fmaxf(__builtin_fmaf(-MB.z, xc.w, MB.z), MB.w * xc.w), mm); \
        m[bi] = mm; \
    } } while (0)

    // steady state: issue q+2, wait current (4 newer outstanding), compute.
#define QSTEP(q, MAC, MBC, MAN, MBN) do { \
    ISSUE(MAN, MBN); \
    asm volatile("s_waitcnt vmcnt(4)" : "+v"(MAC), "+v"(MBC)); \
    COMPUTE(q, MAC, MBC); } while (0)

    QSTEP( 0, A0, B0, A2, B2);
    QSTEP( 1, A1, B1, A0, B0);
    QSTEP( 2, A2, B2, A1, B1);
    QSTEP( 3, A0, B0, A2, B2);
    QSTEP( 4, A1, B1, A0, B0);
    QSTEP( 5, A2, B2, A1, B1);
    QSTEP( 6, A0, B0, A2, B2);
    QSTEP( 7, A1, B1, A0, B0);
    QSTEP( 8, A2, B2, A1, B1);
    QSTEP( 9, A0, B0, A2, B2);
    QSTEP(10, A1, B1, A0, B0);
    QSTEP(11, A2, B2, A1, B1);
    QSTEP(12, A0, B0, A2, B2);
    QSTEP(13, A1, B1, A0, B0);
    // q=14: nothing left to issue; 2 newer (q15) outstanding
    asm volatile("s_waitcnt vmcnt(2)" : "+v"(A2), "+v"(B2));
    COMPUTE(14, A2, B2);
    // q=15: last pair
    asm volatile("s_waitcnt vmcnt(0)" : "+v"(A0), "+v"(B0));
    COMPUTE(15, A0, B0);

#undef QSTEP
#undef COMPUTE
#undef ISSUE
#undef MULOAD

    // ---- epilogue: combine v-quarters, weight, sum over c, accumulate ----
    const int ci = t * 64 + lane;                // 0..127 within chunk
#pragma unroll
    for (int bi = 0; bi < BPB; ++bi)
        red[(s * 128 + ci) * 9 + bi] = m[bi];
    __syncthreads();

    if (wave < 2) {                              // wave w handles c-half t = w
        const float rwc = rw[c];
        float con0, con1, con2, con3, con4, con5, con6, con7;
#define FIN(bi, CON) do { \
        float mm = red[(0 * 128 + ci) * 9 + bi]; \
        mm = fmaxf(mm, red[(1 * 128 + ci) * 9 + bi]); \
        mm = fmaxf(mm, red[(2 * 128 + ci) * 9 + bi]); \
        mm = fmaxf(mm, red[(3 * 128 + ci) * 9 + bi]); \
        float v = rwc * (1.0f - mm); \
        v += __shfl_xor(v, 1, 64);  v += __shfl_xor(v, 2, 64); \
        v += __shfl_xor(v, 4, 64);  v += __shfl_xor(v, 8, 64); \
        v += __shfl_xor(v, 16, 64); v += __shfl_xor(v, 32, 64); \
        CON = v; } while (0)
        FIN(0, con0); FIN(1, con1); FIN(2, con2); FIN(3, con3);
        FIN(4, con4); FIN(5, con5); FIN(6, con6); FIN(7, con7);
#undef FIN
        float t0 = (lane & 1) ? con1 : con0;
        float t1 = (lane & 1) ? con3 : con2;
        float t2 = (lane & 1) ? con5 : con4;
        float t3 = (lane & 1) ? con7 : con6;
        float u0 = (lane & 2) ? t1 : t0;
        float u1 = (lane & 2) ? t3 : t2;
        float sel = (lane & 4) ? u1 : u0;
        if (lane < 8)
            atomicAdd(&out[bg * BPB + lane], sel);  // 8 parallel atomics
    }
}

// ---------- fallback (ws too small): naive but correct ----------
__global__ __launch_bounds__(256) void k_naive(const float* __restrict__ x0,
                                               const float* __restrict__ conj,
                                               const float* __restrict__ rw,
                                               float* __restrict__ out) {
    int b = blockIdx.x;
    int t = threadIdx.x;
    __shared__ float red[256];
    float acc = 0.0f;
    for (int c = t; c < C_; c += 256) {
        float mm = 0.0f;
        for (int v = 0; v < V_; ++v) {
            float mu1 = 1.0f / (1.0f + expf(-conj[(size_t)c * TWOV + v]));
            float mu2 = 1.0f / (1.0f + expf(-conj[(size_t)c * TWOV + V_ + v]));
            float x = x0[(size_t)b * V_ + v];
            mm = fmaxf(mm, fmaxf(mu1 * (1.0f - x), mu2 * x));
        }
        acc += rw[c] * (1.0f - mm);
    }
    red[t] = acc;
    __syncthreads();
    for (int s = 128; s > 0; s >>= 1) {
        if (t < s) red[t] += red[t + s];
        __syncthreads();
    }
    if (t == 0) out[b] = 5.0f + red[0];
}

extern "C" void kernel_launch(void* const* d_in, const int* in_sizes, int n_in,
                              void* d_out, int out_size, void* d_ws, size_t ws_size,
                              hipStream_t stream) {
    const float* x0   = (const float*)d_in[0];
    const float* conj = (const float*)d_in[1];
    const float* rw   = (const float*)d_in[2];
    float* out = (float*)d_out;

    const size_t mu_floats = (size_t)(V_ / 2) * C_ * 4;   // 262144 floats (1 MB)
    const size_t need = mu_floats * sizeof(float);

    if (ws_size < need) {
        k_naive<<<B_, 256, 0, stream>>>(x0, conj, rw, out);
        return;
    }

    f32x4* muT4 = (f32x4*)d_ws;

    k_prep<<<C_, 256, 0, stream>>>(conj, (float2*)muT4, out);
    dim3 grid(NBG, NCH);      // 128 x 4 = 512 blocks = 2/CU, 16 waves/CU
    k_main<<<grid, 512, 0, stream>>>(x0, muT4, rw, out);
}